// Round 6
// baseline (1105.112 us; speedup 1.0000x reference)
//
#include <hip/hip_runtime.h>
#include <math.h>

#define FEAT 128
#define NRBF 20
#define NCONV 3
#define PI_F 3.14159265358979323846f

typedef __attribute__((ext_vector_type(8))) short short8;
typedef __attribute__((ext_vector_type(4))) float floatx4;
typedef unsigned short ushort_t;

__device__ inline float b2f(unsigned short u) {
    union { unsigned int i; float f; } c; c.i = ((unsigned int)u) << 16; return c.f;
}
__device__ inline unsigned short f2b(float x) {
    union { float f; unsigned int i; } c; c.f = x;
    unsigned int u = c.i;
    return (unsigned short)((u + 0x7fffu + ((u >> 16) & 1u)) >> 16);
}

// ---------------------------------------------------------------------------
// Pre-split MFMA GEMM: C[M,N] = A[M,K] @ W[N,K]^T (+bias)(opt silu).
// A given as bf16 hi/lo planes (pre-split by producer); W pre-split.
// acc += Ah*Wh + Ah*Wl + Al*Wh.  Staging = pure uint4 copies.
// 128x128 tile, BK=32, 256 thr = 4 waves, per-wave 64x64 via 4x4 16x16x32.
// Optional second weight set (W2h/W2l) used for tile rows n>=128 (U|V merge),
// with fp32 output routing: n<128 -> C0 (stride cs0), n>=128 -> C1 (stride 128).
// Optional hi/lo output (Chi/Clo) for GEMM-consumed activations.
// ---------------------------------------------------------------------------
__global__ __launch_bounds__(256) void gemm_ps_kernel(
    const ushort_t* __restrict__ Ahg, const ushort_t* __restrict__ Alg,
    const ushort_t* __restrict__ Whi, const ushort_t* __restrict__ Wlo,
    const ushort_t* __restrict__ W2h, const ushort_t* __restrict__ W2l,
    const float* __restrict__ bias,
    float* __restrict__ C0, float* __restrict__ C1,
    ushort_t* __restrict__ Chi, ushort_t* __restrict__ Clo,
    int M, int N, int K, int act)
{
    __shared__ __align__(16) ushort_t Ah[128 * 40];
    __shared__ __align__(16) ushort_t Al[128 * 40];
    __shared__ __align__(16) ushort_t Wh[128 * 40];
    __shared__ __align__(16) ushort_t Wl[128 * 40];
    const int t    = threadIdx.x;
    const int m0   = blockIdx.x * 128;
    const int n0   = blockIdx.y * 128;
    const int wv   = t >> 6;
    const int lane = t & 63;
    const int wm   = (wv >> 1) * 64;
    const int wn   = (wv & 1) * 64;
    const int lr   = lane & 15;
    const int lk   = (lane >> 4) * 8;
    const int srow = t >> 2;          // 64 rows/pass, 2 passes
    const int scol = (t & 3) * 8;

    floatx4 acc[4][4] = {};

    for (int k0 = 0; k0 < K; k0 += 32) {
        #pragma unroll
        for (int h = 0; h < 2; ++h) {
            int r = srow + h * 64;
            int m = m0 + r; if (m >= M) m = M - 1;   // clamp tail
            *(uint4*)(&Ah[r * 40 + scol]) =
                *(const uint4*)(Ahg + (long)m * K + k0 + scol);
            *(uint4*)(&Al[r * 40 + scol]) =
                *(const uint4*)(Alg + (long)m * K + k0 + scol);
            int rg = n0 + r;
            const ushort_t* wsh = Whi;
            const ushort_t* wsl = Wlo;
            long wo = (long)rg * K;
            if (W2h && rg >= 128) { wsh = W2h; wsl = W2l; wo = (long)(rg - 128) * K; }
            *(uint4*)(&Wh[r * 40 + scol]) = *(const uint4*)(wsh + wo + k0 + scol);
            *(uint4*)(&Wl[r * 40 + scol]) = *(const uint4*)(wsl + wo + k0 + scol);
        }
        __syncthreads();
        short8 ah[4], al[4], wh[4], wl[4];
        #pragma unroll
        for (int i = 0; i < 4; ++i) {
            ah[i] = *(const short8*)(&Ah[(wm + i * 16 + lr) * 40 + lk]);
            al[i] = *(const short8*)(&Al[(wm + i * 16 + lr) * 40 + lk]);
            wh[i] = *(const short8*)(&Wh[(wn + i * 16 + lr) * 40 + lk]);
            wl[i] = *(const short8*)(&Wl[(wn + i * 16 + lr) * 40 + lk]);
        }
        #pragma unroll
        for (int i = 0; i < 4; ++i)
            #pragma unroll
            for (int j = 0; j < 4; ++j) {
                acc[i][j] = __builtin_amdgcn_mfma_f32_16x16x32_bf16(
                    ah[i], wh[j], acc[i][j], 0, 0, 0);
                acc[i][j] = __builtin_amdgcn_mfma_f32_16x16x32_bf16(
                    ah[i], wl[j], acc[i][j], 0, 0, 0);
                acc[i][j] = __builtin_amdgcn_mfma_f32_16x16x32_bf16(
                    al[i], wh[j], acc[i][j], 0, 0, 0);
            }
        __syncthreads();
    }

    // epilogue: C/D layout col=lane&15, row=(lane>>4)*4+reg  [m89]
    #pragma unroll
    for (int i = 0; i < 4; ++i) {
        #pragma unroll
        for (int r = 0; r < 4; ++r) {
            int m = m0 + wm + i * 16 + (lane >> 4) * 4 + r;
            if (m >= M) continue;
            #pragma unroll
            for (int j = 0; j < 4; ++j) {
                int n = n0 + wn + j * 16 + (lane & 15);
                float x = acc[i][j][r];
                if (bias) x += bias[n];
                if (act) x *= 1.f / (1.f + __expf(-x));
                if (Chi) {
                    long idx = (long)m * N + n;
                    unsigned short hh = f2b(x);
                    Chi[idx] = hh;
                    Clo[idx] = f2b(x - b2f(hh));
                } else if (C1 && n >= 128) {
                    C1[(long)m * 128 + (n - 128)] = x;
                } else {
                    long cs = C1 ? 128 : N;
                    C0[(long)m * cs + n] = x;
                }
            }
        }
    }
}

// ---------------------------------------------------------------------------
// fp32 -> bf16 hi/lo split (weights, once per launch)
// ---------------------------------------------------------------------------
__global__ __launch_bounds__(256) void split_kernel(
    const float* __restrict__ src, ushort_t* __restrict__ hi,
    ushort_t* __restrict__ lo, int n)
{
    int i = blockIdx.x * blockDim.x + threadIdx.x;
    if (i >= n) return;
    float x = src[i];
    unsigned short h = f2b(x);
    hi[i] = h;
    lo[i] = f2b(x - b2f(h));
}

// ---------------------------------------------------------------------------
// CSR build (unchanged)
// ---------------------------------------------------------------------------
__global__ __launch_bounds__(256) void hist_kernel(
    const int* __restrict__ nbr, int* __restrict__ deg, int Ed)
{
    int e = blockIdx.x * blockDim.x + threadIdx.x;
    if (e >= Ed) return;
    int E = Ed >> 1;
    int i = (e < E) ? nbr[2 * e] : nbr[2 * (e - E) + 1];
    atomicAdd(&deg[i], 1);
}

__device__ inline int wave_incl_scan(int x, int lane)
{
    #pragma unroll
    for (int s = 1; s < 64; s <<= 1) {
        int y = __shfl_up(x, s, 64);
        if (lane >= s) x += y;
    }
    return x;
}

__global__ __launch_bounds__(1024) void scan_kernel(
    const int* __restrict__ deg, int* __restrict__ off,
    int* __restrict__ cursor, int N)
{
    __shared__ int wsum[16];
    __shared__ int carry_s;
    const int t = threadIdx.x;
    const int lane = t & 63;
    const int w = t >> 6;
    if (t == 0) { carry_s = 0; off[0] = 0; }
    __syncthreads();
    for (int base = 0; base < N; base += 1024) {
        int i = base + t;
        int x = (i < N) ? deg[i] : 0;
        int sc = wave_incl_scan(x, lane);
        if (lane == 63) wsum[w] = sc;
        __syncthreads();
        if (w == 0) {
            int v = (lane < 16) ? wsum[lane] : 0;
            int vs = wave_incl_scan(v, lane);
            if (lane < 16) wsum[lane] = vs;
        }
        __syncthreads();
        int waveoff = (w > 0) ? wsum[w - 1] : 0;
        int inc = sc + waveoff + carry_s;
        if (i < N) { off[i + 1] = inc; cursor[i] = inc - x; }
        __syncthreads();
        if (t == 1023) carry_s = inc;
        __syncthreads();
    }
}

__global__ __launch_bounds__(256) void scatter_geom_kernel(
    const int* __restrict__ nbr, const float* __restrict__ xyz,
    int* __restrict__ cursor, int* __restrict__ csr_j,
    float* __restrict__ csr_env, float* __restrict__ csr_unit,
    float* __restrict__ csr_rbfe, int Ed)
{
    int e = blockIdx.x * blockDim.x + threadIdx.x;
    if (e >= Ed) return;
    int E = Ed >> 1;
    int i, j;
    if (e < E) { i = nbr[2 * e];         j = nbr[2 * e + 1]; }
    else       { int u = e - E; i = nbr[2 * u + 1]; j = nbr[2 * u]; }

    int p = atomicAdd(&cursor[i], 1);
    csr_j[p] = j;

    float rx = xyz[3 * j + 0] - xyz[3 * i + 0];
    float ry = xyz[3 * j + 1] - xyz[3 * i + 1];
    float rz = xyz[3 * j + 2] - xyz[3 * i + 2];
    float d   = sqrtf(rx * rx + ry * ry + rz * rz);
    float inv = 1.f / d;
    csr_unit[3 * p + 0] = rx * inv;
    csr_unit[3 * p + 1] = ry * inv;
    csr_unit[3 * p + 2] = rz * inv;
    float ev = (d < 20.f) ? 0.5f * (__cosf(PI_F * d / 20.f) + 1.f) : 0.f;
    csr_env[p] = ev;
    float base = PI_F * d / 20.f;
    #pragma unroll
    for (int k = 0; k < NRBF; ++k)
        csr_rbfe[(long)p * NRBF + k] = ev * __sinf((float)(k + 1) * base) * inv;
}

// ---------------------------------------------------------------------------
// Edge aggregation, atomic-free, fp32 gathers. Now also writes vnew hi/lo
// planes for the downstream U|V GEMM.
// ---------------------------------------------------------------------------
__global__ __launch_bounds__(128) void edge_aggr_kernel(
    const int* __restrict__ off, const int* __restrict__ csr_j,
    const float* __restrict__ csr_env, const float* __restrict__ csr_unit,
    const float* __restrict__ csr_rbfe,
    const float* __restrict__ phi, const float* __restrict__ vold,
    const float* __restrict__ distW, const float* __restrict__ distb,
    float* __restrict__ s, float* __restrict__ vnew,
    ushort_t* __restrict__ vnh, ushort_t* __restrict__ vnl, int N, int SP)
{
    const int f = threadIdx.x;
    float w0c[NRBF], w1c[NRBF], w2c[NRBF];
    const float b0 = distb[f];
    const float b1 = distb[128 + f];
    const float b2 = distb[256 + f];
    #pragma unroll
    for (int k = 0; k < NRBF; ++k) {
        w0c[k] = distW[(long)f * NRBF + k];
        w1c[k] = distW[(long)(128 + f) * NRBF + k];
        w2c[k] = distW[(long)(256 + f) * NRBF + k];
    }

    for (int node = blockIdx.x; node < N; node += gridDim.x) {
        const int p0 = off[node], p1 = off[node + 1];
        float ssum = 0.f, v0 = 0.f, v1 = 0.f, v2 = 0.f;
        for (int p = p0; p < p1; ++p) {
            int j = csr_j[p];
            float ev = csr_env[p];
            float ux = csr_unit[3 * p + 0];
            float uy = csr_unit[3 * p + 1];
            float uz = csr_unit[3 * p + 2];
            const float* rb = csr_rbfe + (long)p * NRBF;
            float w0 = ev * b0, w1 = ev * b1, w2 = ev * b2;
            #pragma unroll
            for (int k = 0; k < NRBF; ++k) {
                float r = rb[k];
                w0 += r * w0c[k];
                w1 += r * w1c[k];
                w2 += r * w2c[k];
            }
            long jb = (long)j * 384;
            float i0 = phi[jb + f]       * w0;
            float i1 = phi[jb + 128 + f] * w1;
            float i2 = phi[jb + 256 + f] * w2;
            long jv = (long)j * FEAT + f;
            ssum += i1;
            v0 += i2 * ux + i0 * vold[jv];
            v1 += i2 * uy + i0 * vold[SP + jv];
            v2 += i2 * uz + i0 * vold[2 * SP + jv];
        }
        long iv = (long)node * FEAT + f;
        s[iv] += ssum;
        float n0 = vold[iv]          + v0;
        float n1 = vold[SP + iv]     + v1;
        float n2 = vold[2 * SP + iv] + v2;
        vnew[iv]          = n0;
        vnew[SP + iv]     = n1;
        vnew[2 * SP + iv] = n2;
        unsigned short h0 = f2b(n0), h1 = f2b(n1), h2 = f2b(n2);
        vnh[iv]          = h0;  vnl[iv]          = f2b(n0 - b2f(h0));
        vnh[SP + iv]     = h1;  vnl[SP + iv]     = f2b(n1 - b2f(h1));
        vnh[2 * SP + iv] = h2;  vnl[2 * SP + iv] = f2b(n2 - b2f(h2));
    }
}

// ---------------------------------------------------------------------------
// Elementwise kernels
// ---------------------------------------------------------------------------
__global__ __launch_bounds__(256) void init_s_kernel(
    const float* __restrict__ cg_s, float* __restrict__ s,
    ushort_t* __restrict__ sh, ushort_t* __restrict__ sl,
    float* __restrict__ vA, int nS, int nV)
{
    int idx = blockIdx.x * blockDim.x + threadIdx.x;
    if (idx < nS) {
        float x = cg_s[idx];
        s[idx] = x;
        unsigned short h = f2b(x);
        sh[idx] = h; sl[idx] = f2b(x - b2f(h));
    }
    if (idx < nV) vA[idx] = 0.f;
}

__global__ __launch_bounds__(256) void cat_norm_kernel(
    const float* __restrict__ s, const float* __restrict__ vv,
    ushort_t* __restrict__ cath, ushort_t* __restrict__ catl, int SP)
{
    int idx = blockIdx.x * blockDim.x + threadIdx.x;
    if (idx >= SP) return;
    int n = idx >> 7, g = idx & 127;
    float a0 = vv[idx], a1 = vv[SP + idx], a2 = vv[2 * SP + idx];
    float x0 = s[idx];
    float x1 = sqrtf(a0 * a0 + a1 * a1 + a2 * a2);
    unsigned short h0 = f2b(x0), h1 = f2b(x1);
    long base = (long)n * 256;
    cath[base + g]       = h0;  catl[base + g]       = f2b(x0 - b2f(h0));
    cath[base + 128 + g] = h1;  catl[base + 128 + g] = f2b(x1 - b2f(h1));
}

__global__ __launch_bounds__(256) void update_sv_kernel(
    float* __restrict__ s, ushort_t* __restrict__ sh, ushort_t* __restrict__ sl,
    float* __restrict__ v,
    const float* __restrict__ uv, const float* __restrict__ vv,
    const float* __restrict__ a, int SP)
{
    int idx = blockIdx.x * blockDim.x + threadIdx.x;
    if (idx >= SP) return;
    int n = idx >> 7, g = idx & 127;
    float u0 = uv[idx], u1 = uv[SP + idx], u2 = uv[2 * SP + idx];
    float w0 = vv[idx], w1 = vv[SP + idx], w2 = vv[2 * SP + idx];
    long ab = (long)n * 384;
    float dot = u0 * w0 + u1 * w1 + u2 * w2;
    float sn = s[idx] + dot * a[ab + 128 + g] + a[ab + 256 + g];
    s[idx] = sn;
    unsigned short hh = f2b(sn);
    sh[idx] = hh; sl[idx] = f2b(sn - b2f(hh));
    float g0 = a[ab + g];
    v[idx]          += u0 * g0;
    v[SP + idx]     += u1 * g0;
    v[2 * SP + idx] += u2 * g0;
}

__global__ __launch_bounds__(256) void write_out_kernel(
    const float* __restrict__ vfin, float* __restrict__ outv, int SP)
{
    int idx = blockIdx.x * blockDim.x + threadIdx.x;
    if (idx >= SP) return;
    outv[(long)idx * 3 + 0] = vfin[idx];
    outv[(long)idx * 3 + 1] = vfin[SP + idx];
    outv[(long)idx * 3 + 2] = vfin[2 * SP + idx];
}

// ---------------------------------------------------------------------------
extern "C" void kernel_launch(void* const* d_in, const int* in_sizes, int n_in,
                              void* d_out, int out_size, void* d_ws, size_t ws_size,
                              hipStream_t stream)
{
    const float* xyz     = (const float*)d_in[0];
    const int*   nbr     = (const int*)  d_in[1];
    const float* cg_s    = (const float*)d_in[2];
    const float* msg_W1  = (const float*)d_in[3];
    const float* msg_b1  = (const float*)d_in[4];
    const float* msg_W2  = (const float*)d_in[5];
    const float* msg_b2  = (const float*)d_in[6];
    const float* dist_W  = (const float*)d_in[7];
    const float* dist_b  = (const float*)d_in[8];
    const float* upd_U   = (const float*)d_in[9];
    const float* upd_V   = (const float*)d_in[10];
    const float* upd_sW1 = (const float*)d_in[11];
    const float* upd_sb1 = (const float*)d_in[12];
    const float* upd_sW2 = (const float*)d_in[13];
    const float* upd_sb2 = (const float*)d_in[14];

    const int E  = in_sizes[1] / 2;
    const int Ed = 2 * E;
    const int N  = in_sizes[2] / FEAT;
    const int SP = N * FEAT;

    float* s    = (float*)d_out;
    float* outv = (float*)d_out + (long)SP;
    float* u_v  = outv;   // alias: u_v planes dead by output time

    // workspace carve-up (fp32-element units, 256-elem aligned)
    float* w = (float*)d_ws;
    size_t off_ = 0;
    auto alloc = [&](size_t nelem) {
        float* p = w + off_;
        off_ += (nelem + 255) & ~(size_t)255;
        return p;
    };
    auto allocb = [&](size_t nelem) {   // bf16 elements
        return (ushort_t*)alloc((nelem + 1) / 2);
    };
    int*   deg      = (int*)alloc((size_t)N);
    int*   off      = (int*)alloc((size_t)N + 1);
    int*   cursor   = (int*)alloc((size_t)N);
    int*   csr_j    = (int*)alloc((size_t)Ed);
    float* csr_env  = alloc((size_t)Ed);
    float* csr_unit = alloc((size_t)Ed * 3);
    float* csr_rbfe = alloc((size_t)Ed * NRBF);
    float* phi      = alloc((size_t)N * 384);   // reused for 'a'
    float* v_v      = alloc((size_t)3 * SP);
    float* vA       = alloc((size_t)3 * SP);
    float* vB       = alloc((size_t)3 * SP);
    // bf16 hi/lo activation planes
    ushort_t* s_h  = allocb((size_t)SP);
    ushort_t* s_l  = allocb((size_t)SP);
    ushort_t* h_h  = allocb((size_t)SP);
    ushort_t* h_l  = allocb((size_t)SP);
    ushort_t* cath = allocb((size_t)N * 256);
    ushort_t* catl = allocb((size_t)N * 256);
    ushort_t* vnh  = allocb((size_t)3 * SP);
    ushort_t* vnl  = allocb((size_t)3 * SP);
    const int n1 = NCONV * FEAT * FEAT;
    const int n2 = NCONV * 3 * FEAT * FEAT;
    const int n3 = NCONV * FEAT * 2 * FEAT;
    ushort_t* w1h  = allocb((size_t)n1);
    ushort_t* w1l  = allocb((size_t)n1);
    ushort_t* w2h  = allocb((size_t)n2);
    ushort_t* w2l  = allocb((size_t)n2);
    ushort_t* uh   = allocb((size_t)n1);
    ushort_t* ul   = allocb((size_t)n1);
    ushort_t* vh   = allocb((size_t)n1);
    ushort_t* vl   = allocb((size_t)n1);
    ushort_t* sw1h = allocb((size_t)n3);
    ushort_t* sw1l = allocb((size_t)n3);
    ushort_t* sw2h = allocb((size_t)n2);
    ushort_t* sw2l = allocb((size_t)n2);
    (void)ws_size; (void)n_in; (void)out_size;

    // weight split (once per launch)
    split_kernel<<<(n1 + 255) / 256, 256, 0, stream>>>(msg_W1, w1h, w1l, n1);
    split_kernel<<<(n2 + 255) / 256, 256, 0, stream>>>(msg_W2, w2h, w2l, n2);
    split_kernel<<<(n1 + 255) / 256, 256, 0, stream>>>(upd_U, uh, ul, n1);
    split_kernel<<<(n1 + 255) / 256, 256, 0, stream>>>(upd_V, vh, vl, n1);
    split_kernel<<<(n3 + 255) / 256, 256, 0, stream>>>(upd_sW1, sw1h, sw1l, n3);
    split_kernel<<<(n2 + 255) / 256, 256, 0, stream>>>(upd_sW2, sw2h, sw2l, n2);

    // init s <- cg_s (+hi/lo), vA <- 0
    {
        int n = 3 * SP;
        init_s_kernel<<<(n + 255) / 256, 256, 0, stream>>>(
            cg_s, s, s_h, s_l, vA, SP, n);
    }

    // CSR build (once per launch)
    hipMemsetAsync(deg, 0, (size_t)N * sizeof(int), stream);
    hist_kernel<<<(Ed + 255) / 256, 256, 0, stream>>>(nbr, deg, Ed);
    scan_kernel<<<1, 1024, 0, stream>>>(deg, off, cursor, N);
    scatter_geom_kernel<<<(Ed + 255) / 256, 256, 0, stream>>>(
        nbr, xyz, cursor, csr_j, csr_env, csr_unit, csr_rbfe, Ed);

    float* vold = vA;
    float* vnew = vB;
    dim3 gN128((N + 127) / 128, 1);
    dim3 gN384((N + 127) / 128, 3);
    dim3 gUV((3 * N + 127) / 128, 2);
    const int aggr_blocks = 2560;

    for (int l = 0; l < NCONV; ++l) {
        const float* b1  = msg_b1  + (long)l * FEAT;
        const float* b2  = msg_b2  + (long)l * 3 * FEAT;
        const float* dW  = dist_W  + (long)l * 3 * FEAT * NRBF;
        const float* db  = dist_b  + (long)l * 3 * FEAT;
        const float* sb1 = upd_sb1 + (long)l * FEAT;
        const float* sb2 = upd_sb2 + (long)l * 3 * FEAT;
        const long o1 = (long)l * FEAT * FEAT;
        const long o2 = (long)l * 3 * FEAT * FEAT;
        const long o3 = (long)l * FEAT * 2 * FEAT;

        // phi-MLP: s -> h (hi/lo), h -> phi (fp32)
        gemm_ps_kernel<<<gN128, 256, 0, stream>>>(
            s_h, s_l, w1h + o1, w1l + o1, nullptr, nullptr, b1,
            nullptr, nullptr, h_h, h_l, N, FEAT, FEAT, 1);
        gemm_ps_kernel<<<gN384, 256, 0, stream>>>(
            h_h, h_l, w2h + o2, w2l + o2, nullptr, nullptr, b2,
            phi, nullptr, nullptr, nullptr, N, 3 * FEAT, FEAT, 0);

        // atomic-free message aggregation (fp32 + vnew hi/lo)
        edge_aggr_kernel<<<aggr_blocks, 128, 0, stream>>>(
            off, csr_j, csr_env, csr_unit, csr_rbfe, phi, vold,
            dW, db, s, vnew, vnh, vnl, N, SP);

        // u_v and v_v in ONE dispatch: N=256, tile-y 0 = U rows, tile-y 1 = V
        gemm_ps_kernel<<<gUV, 256, 0, stream>>>(
            vnh, vnl, uh + o1, ul + o1, vh + o1, vl + o1, nullptr,
            u_v, v_v, nullptr, nullptr, 3 * N, 256, FEAT, 0);

        // gate MLP: cat -> h (hi/lo), h -> a (fp32, in 'phi' buffer)
        cat_norm_kernel<<<(SP + 255) / 256, 256, 0, stream>>>(
            s, v_v, cath, catl, SP);
        gemm_ps_kernel<<<gN128, 256, 0, stream>>>(
            cath, catl, sw1h + o3, sw1l + o3, nullptr, nullptr, sb1,
            nullptr, nullptr, h_h, h_l, N, FEAT, 2 * FEAT, 1);
        gemm_ps_kernel<<<gN384, 256, 0, stream>>>(
            h_h, h_l, sw2h + o2, sw2l + o2, nullptr, nullptr, sb2,
            phi, nullptr, nullptr, nullptr, N, 3 * FEAT, FEAT, 0);

        // final update ('phi' holds 'a'); refreshes s hi/lo for next layer
        update_sv_kernel<<<(SP + 255) / 256, 256, 0, stream>>>(
            s, s_h, s_l, vnew, u_v, v_v, phi, SP);

        float* tmp = vold; vold = vnew; vnew = tmp;
    }

    write_out_kernel<<<(SP + 255) / 256, 256, 0, stream>>>(vold, outv, SP);
}

// Round 8
// 1042.512 us; speedup vs baseline: 1.0600x; 1.0600x over previous
//
#include <hip/hip_runtime.h>
#include <math.h>

#define FEAT 128
#define NRBF 20
#define NCONV 3
#define PI_F 3.14159265358979323846f

typedef __attribute__((ext_vector_type(8))) short short8;
typedef __attribute__((ext_vector_type(4))) float floatx4;
typedef unsigned short ushort_t;

__device__ inline float b2f(unsigned short u) {
    union { unsigned int i; float f; } c; c.i = ((unsigned int)u) << 16; return c.f;
}
__device__ inline unsigned short f2b(float x) {
    union { float f; unsigned int i; } c; c.f = x;
    unsigned int u = c.i;
    return (unsigned short)((u + 0x7fffu + ((u >> 16) & 1u)) >> 16);
}

// ---------------------------------------------------------------------------
// Pre-split MFMA GEMM: C[M,N] = A[M,K] @ W[N,K]^T (+bias)(opt silu).
// A as bf16 hi/lo planes; W pre-split. acc += Ah*Wh + Ah*Wl + Al*Wh.
// 128x128 tile, BK=32, 256 thr = 4 waves, per-wave 64x64 via 4x4 16x16x32.
// Output modes: Chi!=0 -> bf16 hi (+lo if Clo!=0); else fp32 C0/C1 routing
// (C1 used for n>=128 with the dual-weight U|V merge).
// ---------------------------------------------------------------------------
__global__ __launch_bounds__(256) void gemm_ps_kernel(
    const ushort_t* __restrict__ Ahg, const ushort_t* __restrict__ Alg,
    const ushort_t* __restrict__ Whi, const ushort_t* __restrict__ Wlo,
    const ushort_t* __restrict__ W2h, const ushort_t* __restrict__ W2l,
    const float* __restrict__ bias,
    float* __restrict__ C0, float* __restrict__ C1,
    ushort_t* __restrict__ Chi, ushort_t* __restrict__ Clo,
    int M, int N, int K, int act)
{
    __shared__ __align__(16) ushort_t Ah[128 * 40];
    __shared__ __align__(16) ushort_t Al[128 * 40];
    __shared__ __align__(16) ushort_t Wh[128 * 40];
    __shared__ __align__(16) ushort_t Wl[128 * 40];
    const int t    = threadIdx.x;
    const int m0   = blockIdx.x * 128;
    const int n0   = blockIdx.y * 128;
    const int wv   = t >> 6;
    const int lane = t & 63;
    const int wm   = (wv >> 1) * 64;
    const int wn   = (wv & 1) * 64;
    const int lr   = lane & 15;
    const int lk   = (lane >> 4) * 8;
    const int srow = t >> 2;          // 64 rows/pass, 2 passes
    const int scol = (t & 3) * 8;

    floatx4 acc[4][4] = {};

    for (int k0 = 0; k0 < K; k0 += 32) {
        #pragma unroll
        for (int h = 0; h < 2; ++h) {
            int r = srow + h * 64;
            int m = m0 + r; if (m >= M) m = M - 1;   // clamp tail
            *(uint4*)(&Ah[r * 40 + scol]) =
                *(const uint4*)(Ahg + (long)m * K + k0 + scol);
            *(uint4*)(&Al[r * 40 + scol]) =
                *(const uint4*)(Alg + (long)m * K + k0 + scol);
            int rg = n0 + r;
            const ushort_t* wsh = Whi;
            const ushort_t* wsl = Wlo;
            long wo = (long)rg * K;
            if (W2h && rg >= 128) { wsh = W2h; wsl = W2l; wo = (long)(rg - 128) * K; }
            *(uint4*)(&Wh[r * 40 + scol]) = *(const uint4*)(wsh + wo + k0 + scol);
            *(uint4*)(&Wl[r * 40 + scol]) = *(const uint4*)(wsl + wo + k0 + scol);
        }
        __syncthreads();
        short8 ah[4], al[4], wh[4], wl[4];
        #pragma unroll
        for (int i = 0; i < 4; ++i) {
            ah[i] = *(const short8*)(&Ah[(wm + i * 16 + lr) * 40 + lk]);
            al[i] = *(const short8*)(&Al[(wm + i * 16 + lr) * 40 + lk]);
            wh[i] = *(const short8*)(&Wh[(wn + i * 16 + lr) * 40 + lk]);
            wl[i] = *(const short8*)(&Wl[(wn + i * 16 + lr) * 40 + lk]);
        }
        #pragma unroll
        for (int i = 0; i < 4; ++i)
            #pragma unroll
            for (int j = 0; j < 4; ++j) {
                acc[i][j] = __builtin_amdgcn_mfma_f32_16x16x32_bf16(
                    ah[i], wh[j], acc[i][j], 0, 0, 0);
                acc[i][j] = __builtin_amdgcn_mfma_f32_16x16x32_bf16(
                    ah[i], wl[j], acc[i][j], 0, 0, 0);
                acc[i][j] = __builtin_amdgcn_mfma_f32_16x16x32_bf16(
                    al[i], wh[j], acc[i][j], 0, 0, 0);
            }
        __syncthreads();
    }

    // epilogue: C/D layout col=lane&15, row=(lane>>4)*4+reg  [m89]
    #pragma unroll
    for (int i = 0; i < 4; ++i) {
        #pragma unroll
        for (int r = 0; r < 4; ++r) {
            int m = m0 + wm + i * 16 + (lane >> 4) * 4 + r;
            if (m >= M) continue;
            #pragma unroll
            for (int j = 0; j < 4; ++j) {
                int n = n0 + wn + j * 16 + (lane & 15);
                float x = acc[i][j][r];
                if (bias) x += bias[n];
                if (act) x *= 1.f / (1.f + __expf(-x));
                if (Chi) {
                    long idx = (long)m * N + n;
                    unsigned short hh = f2b(x);
                    Chi[idx] = hh;
                    if (Clo) Clo[idx] = f2b(x - b2f(hh));
                } else if (C1 && n >= 128) {
                    C1[(long)m * 128 + (n - 128)] = x;
                } else {
                    long cs = C1 ? 128 : N;
                    C0[(long)m * cs + n] = x;
                }
            }
        }
    }
}

// ---------------------------------------------------------------------------
// fp32 -> bf16 hi/lo split (weights, once per launch)
// ---------------------------------------------------------------------------
__global__ __launch_bounds__(256) void split_kernel(
    const float* __restrict__ src, ushort_t* __restrict__ hi,
    ushort_t* __restrict__ lo, int n)
{
    int i = blockIdx.x * blockDim.x + threadIdx.x;
    if (i >= n) return;
    float x = src[i];
    unsigned short h = f2b(x);
    hi[i] = h;
    lo[i] = f2b(x - b2f(h));
}

// ---------------------------------------------------------------------------
// CSR build
// ---------------------------------------------------------------------------
__global__ __launch_bounds__(256) void hist_kernel(
    const int* __restrict__ nbr, int* __restrict__ deg, int Ed)
{
    int e = blockIdx.x * blockDim.x + threadIdx.x;
    if (e >= Ed) return;
    int E = Ed >> 1;
    int i = (e < E) ? nbr[2 * e] : nbr[2 * (e - E) + 1];
    atomicAdd(&deg[i], 1);
}

__device__ inline int wave_incl_scan(int x, int lane)
{
    #pragma unroll
    for (int s = 1; s < 64; s <<= 1) {
        int y = __shfl_up(x, s, 64);
        if (lane >= s) x += y;
    }
    return x;
}

__global__ __launch_bounds__(1024) void scan_kernel(
    const int* __restrict__ deg, int* __restrict__ off,
    int* __restrict__ cursor, int N)
{
    __shared__ int wsum[16];
    __shared__ int carry_s;
    const int t = threadIdx.x;
    const int lane = t & 63;
    const int w = t >> 6;
    if (t == 0) { carry_s = 0; off[0] = 0; }
    __syncthreads();
    for (int base = 0; base < N; base += 1024) {
        int i = base + t;
        int x = (i < N) ? deg[i] : 0;
        int sc = wave_incl_scan(x, lane);
        if (lane == 63) wsum[w] = sc;
        __syncthreads();
        if (w == 0) {
            int v = (lane < 16) ? wsum[lane] : 0;
            int vs = wave_incl_scan(v, lane);
            if (lane < 16) wsum[lane] = vs;
        }
        __syncthreads();
        int waveoff = (w > 0) ? wsum[w - 1] : 0;
        int inc = sc + waveoff + carry_s;
        if (i < N) { off[i + 1] = inc; cursor[i] = inc - x; }
        __syncthreads();
        if (t == 1023) carry_s = inc;
        __syncthreads();
    }
}

__global__ __launch_bounds__(256) void scatter_geom_kernel(
    const int* __restrict__ nbr, const float* __restrict__ xyz,
    int* __restrict__ cursor, int* __restrict__ csr_j,
    float* __restrict__ csr_env, float* __restrict__ csr_unit,
    float* __restrict__ csr_rbfe, int Ed)
{
    int e = blockIdx.x * blockDim.x + threadIdx.x;
    if (e >= Ed) return;
    int E = Ed >> 1;
    int i, j;
    if (e < E) { i = nbr[2 * e];         j = nbr[2 * e + 1]; }
    else       { int u = e - E; i = nbr[2 * u + 1]; j = nbr[2 * u]; }

    int p = atomicAdd(&cursor[i], 1);
    csr_j[p] = j;

    float rx = xyz[3 * j + 0] - xyz[3 * i + 0];
    float ry = xyz[3 * j + 1] - xyz[3 * i + 1];
    float rz = xyz[3 * j + 2] - xyz[3 * i + 2];
    float d   = sqrtf(rx * rx + ry * ry + rz * rz);
    float inv = 1.f / d;
    csr_unit[3 * p + 0] = rx * inv;
    csr_unit[3 * p + 1] = ry * inv;
    csr_unit[3 * p + 2] = rz * inv;
    float ev = (d < 20.f) ? 0.5f * (__cosf(PI_F * d / 20.f) + 1.f) : 0.f;
    csr_env[p] = ev;
    float base = PI_F * d / 20.f;
    #pragma unroll
    for (int k = 0; k < NRBF; ++k)
        csr_rbfe[(long)p * NRBF + k] = ev * __sinf((float)(k + 1) * base) * inv;
}

// ---------------------------------------------------------------------------
// Edge aggregation, atomic-free. phi gathered bf16 (linear error path);
// v gathered fp32 (quadratic error path kept exact). Double-buffered v.
// Emits vnh/vnl split for the U|V GEMM.
// ---------------------------------------------------------------------------
__global__ __launch_bounds__(128) void edge_aggr_kernel(
    const int* __restrict__ off, const int* __restrict__ csr_j,
    const float* __restrict__ csr_env, const float* __restrict__ csr_unit,
    const float* __restrict__ csr_rbfe,
    const ushort_t* __restrict__ phib, const float* __restrict__ vold,
    const float* __restrict__ distW, const float* __restrict__ distb,
    float* __restrict__ s, float* __restrict__ vnew,
    ushort_t* __restrict__ vnh, ushort_t* __restrict__ vnl, int N, int SP)
{
    const int f = threadIdx.x;
    float w0c[NRBF], w1c[NRBF], w2c[NRBF];
    const float b0 = distb[f];
    const float b1 = distb[128 + f];
    const float b2 = distb[256 + f];
    #pragma unroll
    for (int k = 0; k < NRBF; ++k) {
        w0c[k] = distW[(long)f * NRBF + k];
        w1c[k] = distW[(long)(128 + f) * NRBF + k];
        w2c[k] = distW[(long)(256 + f) * NRBF + k];
    }

    for (int node = blockIdx.x; node < N; node += gridDim.x) {
        const int p0 = off[node], p1 = off[node + 1];
        float ssum = 0.f, v0 = 0.f, v1 = 0.f, v2 = 0.f;
        for (int p = p0; p < p1; ++p) {
            int j = csr_j[p];
            float ev = csr_env[p];
            float ux = csr_unit[3 * p + 0];
            float uy = csr_unit[3 * p + 1];
            float uz = csr_unit[3 * p + 2];
            const float* rb = csr_rbfe + (long)p * NRBF;
            float w0 = ev * b0, w1 = ev * b1, w2 = ev * b2;
            #pragma unroll
            for (int k = 0; k < NRBF; ++k) {
                float r = rb[k];
                w0 += r * w0c[k];
                w1 += r * w1c[k];
                w2 += r * w2c[k];
            }
            long jb = (long)j * 384;
            float i0 = b2f(phib[jb + f])       * w0;
            float i1 = b2f(phib[jb + 128 + f]) * w1;
            float i2 = b2f(phib[jb + 256 + f]) * w2;
            long jv = (long)j * FEAT + f;
            ssum += i1;
            v0 += i2 * ux + i0 * vold[jv];
            v1 += i2 * uy + i0 * vold[SP + jv];
            v2 += i2 * uz + i0 * vold[2 * SP + jv];
        }
        long iv = (long)node * FEAT + f;
        s[iv] += ssum;
        float n0 = vold[iv]          + v0;
        float n1 = vold[SP + iv]     + v1;
        float n2 = vold[2 * SP + iv] + v2;
        vnew[iv]          = n0;
        vnew[SP + iv]     = n1;
        vnew[2 * SP + iv] = n2;
        unsigned short h0 = f2b(n0), h1 = f2b(n1), h2 = f2b(n2);
        vnh[iv]          = h0;  vnl[iv]          = f2b(n0 - b2f(h0));
        vnh[SP + iv]     = h1;  vnl[SP + iv]     = f2b(n1 - b2f(h1));
        vnh[2 * SP + iv] = h2;  vnl[2 * SP + iv] = f2b(n2 - b2f(h2));
    }
}

// ---------------------------------------------------------------------------
// Elementwise kernels
// ---------------------------------------------------------------------------
__global__ __launch_bounds__(256) void init_s_kernel(
    const float* __restrict__ cg_s, float* __restrict__ s,
    ushort_t* __restrict__ sh, ushort_t* __restrict__ sl,
    float* __restrict__ vA, int nS, int nV)
{
    int idx = blockIdx.x * blockDim.x + threadIdx.x;
    if (idx < nS) {
        float x = cg_s[idx];
        s[idx] = x;
        unsigned short h = f2b(x);
        sh[idx] = h; sl[idx] = f2b(x - b2f(h));
    }
    if (idx < nV) vA[idx] = 0.f;
}

__global__ __launch_bounds__(256) void cat_norm_kernel(
    const float* __restrict__ s, const float* __restrict__ vv,
    ushort_t* __restrict__ cath, ushort_t* __restrict__ catl, int SP)
{
    int idx = blockIdx.x * blockDim.x + threadIdx.x;
    if (idx >= SP) return;
    int n = idx >> 7, g = idx & 127;
    float a0 = vv[idx], a1 = vv[SP + idx], a2 = vv[2 * SP + idx];
    float x0 = s[idx];
    float x1 = sqrtf(a0 * a0 + a1 * a1 + a2 * a2);
    unsigned short h0 = f2b(x0), h1 = f2b(x1);
    long base = (long)n * 256;
    cath[base + g]       = h0;  catl[base + g]       = f2b(x0 - b2f(h0));
    cath[base + 128 + g] = h1;  catl[base + 128 + g] = f2b(x1 - b2f(h1));
}

__global__ __launch_bounds__(256) void update_sv_kernel(
    float* __restrict__ s, ushort_t* __restrict__ sh, ushort_t* __restrict__ sl,
    float* __restrict__ v,
    const float* __restrict__ uv, const float* __restrict__ vv,
    const float* __restrict__ a, int SP)
{
    int idx = blockIdx.x * blockDim.x + threadIdx.x;
    if (idx >= SP) return;
    int n = idx >> 7, g = idx & 127;
    float u0 = uv[idx], u1 = uv[SP + idx], u2 = uv[2 * SP + idx];
    float w0 = vv[idx], w1 = vv[SP + idx], w2 = vv[2 * SP + idx];
    long ab = (long)n * 384;
    float dot = u0 * w0 + u1 * w1 + u2 * w2;
    float sn = s[idx] + dot * a[ab + 128 + g] + a[ab + 256 + g];
    s[idx] = sn;
    unsigned short hh = f2b(sn);
    sh[idx] = hh; sl[idx] = f2b(sn - b2f(hh));
    float g0 = a[ab + g];
    v[idx]          += u0 * g0;
    v[SP + idx]     += u1 * g0;
    v[2 * SP + idx] += u2 * g0;
}

__global__ __launch_bounds__(256) void write_out_kernel(
    const float* __restrict__ vfin, float* __restrict__ outv, int SP)
{
    int idx = blockIdx.x * blockDim.x + threadIdx.x;
    if (idx >= SP) return;
    outv[(long)idx * 3 + 0] = vfin[idx];
    outv[(long)idx * 3 + 1] = vfin[SP + idx];
    outv[(long)idx * 3 + 2] = vfin[2 * SP + idx];
}

// ---------------------------------------------------------------------------
extern "C" void kernel_launch(void* const* d_in, const int* in_sizes, int n_in,
                              void* d_out, int out_size, void* d_ws, size_t ws_size,
                              hipStream_t stream)
{
    const float* xyz     = (const float*)d_in[0];
    const int*   nbr     = (const int*)  d_in[1];
    const float* cg_s    = (const float*)d_in[2];
    const float* msg_W1  = (const float*)d_in[3];
    const float* msg_b1  = (const float*)d_in[4];
    const float* msg_W2  = (const float*)d_in[5];
    const float* msg_b2  = (const float*)d_in[6];
    const float* dist_W  = (const float*)d_in[7];
    const float* dist_b  = (const float*)d_in[8];
    const float* upd_U   = (const float*)d_in[9];
    const float* upd_V   = (const float*)d_in[10];
    const float* upd_sW1 = (const float*)d_in[11];
    const float* upd_sb1 = (const float*)d_in[12];
    const float* upd_sW2 = (const float*)d_in[13];
    const float* upd_sb2 = (const float*)d_in[14];

    const int E  = in_sizes[1] / 2;
    const int Ed = 2 * E;
    const int N  = in_sizes[2] / FEAT;
    const int SP = N * FEAT;

    float* s    = (float*)d_out;
    float* outv = (float*)d_out + (long)SP;
    float* u_v  = outv;   // alias: u_v planes dead by output time

    // workspace carve-up (fp32-element units, 256-elem aligned)
    float* w = (float*)d_ws;
    size_t off_ = 0;
    auto alloc = [&](size_t nelem) {
        float* p = w + off_;
        off_ += (nelem + 255) & ~(size_t)255;
        return p;
    };
    auto allocb = [&](size_t nelem) {   // bf16 elements
        return (ushort_t*)alloc((nelem + 1) / 2);
    };
    int*   deg      = (int*)alloc((size_t)N);
    int*   off      = (int*)alloc((size_t)N + 1);
    int*   cursor   = (int*)alloc((size_t)N);
    int*   csr_j    = (int*)alloc((size_t)Ed);
    float* csr_env  = alloc((size_t)Ed);
    float* csr_unit = alloc((size_t)Ed * 3);
    float* csr_rbfe = alloc((size_t)Ed * NRBF);
    float* a_buf    = alloc((size_t)N * 384);
    float* v_v      = alloc((size_t)3 * SP);
    float* vA       = alloc((size_t)3 * SP);
    float* vB       = alloc((size_t)3 * SP);
    // bf16 planes
    ushort_t* s_h   = allocb((size_t)SP);
    ushort_t* s_l   = allocb((size_t)SP);
    ushort_t* h_h   = allocb((size_t)SP);
    ushort_t* h_l   = allocb((size_t)SP);
    ushort_t* cath  = allocb((size_t)N * 256);
    ushort_t* catl  = allocb((size_t)N * 256);
    ushort_t* phi_b = allocb((size_t)N * 384);
    ushort_t* vnh   = allocb((size_t)3 * SP);
    ushort_t* vnl   = allocb((size_t)3 * SP);
    const int n1 = NCONV * FEAT * FEAT;
    const int n2 = NCONV * 3 * FEAT * FEAT;
    const int n3 = NCONV * FEAT * 2 * FEAT;
    ushort_t* w1h  = allocb((size_t)n1);
    ushort_t* w1l  = allocb((size_t)n1);
    ushort_t* w2h  = allocb((size_t)n2);
    ushort_t* w2l  = allocb((size_t)n2);
    ushort_t* uh   = allocb((size_t)n1);
    ushort_t* ul   = allocb((size_t)n1);
    ushort_t* vh   = allocb((size_t)n1);
    ushort_t* vl   = allocb((size_t)n1);
    ushort_t* sw1h = allocb((size_t)n3);
    ushort_t* sw1l = allocb((size_t)n3);
    ushort_t* sw2h = allocb((size_t)n2);
    ushort_t* sw2l = allocb((size_t)n2);
    (void)ws_size; (void)n_in; (void)out_size;

    // weight split (once per launch)
    split_kernel<<<(n1 + 255) / 256, 256, 0, stream>>>(msg_W1, w1h, w1l, n1);
    split_kernel<<<(n2 + 255) / 256, 256, 0, stream>>>(msg_W2, w2h, w2l, n2);
    split_kernel<<<(n1 + 255) / 256, 256, 0, stream>>>(upd_U, uh, ul, n1);
    split_kernel<<<(n1 + 255) / 256, 256, 0, stream>>>(upd_V, vh, vl, n1);
    split_kernel<<<(n3 + 255) / 256, 256, 0, stream>>>(upd_sW1, sw1h, sw1l, n3);
    split_kernel<<<(n2 + 255) / 256, 256, 0, stream>>>(upd_sW2, sw2h, sw2l, n2);

    // init s <- cg_s (+hi/lo), vA <- 0
    {
        int n = 3 * SP;
        init_s_kernel<<<(n + 255) / 256, 256, 0, stream>>>(
            cg_s, s, s_h, s_l, vA, SP, n);
    }

    // CSR build (once per launch)
    hipMemsetAsync(deg, 0, (size_t)N * sizeof(int), stream);
    hist_kernel<<<(Ed + 255) / 256, 256, 0, stream>>>(nbr, deg, Ed);
    scan_kernel<<<1, 1024, 0, stream>>>(deg, off, cursor, N);
    scatter_geom_kernel<<<(Ed + 255) / 256, 256, 0, stream>>>(
        nbr, xyz, cursor, csr_j, csr_env, csr_unit, csr_rbfe, Ed);

    float* vold = vA;
    float* vnew = vB;
    dim3 gN128((N + 127) / 128, 1);
    dim3 gN384((N + 127) / 128, 3);
    dim3 gUV((3 * N + 127) / 128, 2);

    for (int l = 0; l < NCONV; ++l) {
        const float* b1  = msg_b1  + (long)l * FEAT;
        const float* b2  = msg_b2  + (long)l * 3 * FEAT;
        const float* dW  = dist_W  + (long)l * 3 * FEAT * NRBF;
        const float* db  = dist_b  + (long)l * 3 * FEAT;
        const float* sb1 = upd_sb1 + (long)l * FEAT;
        const float* sb2 = upd_sb2 + (long)l * 3 * FEAT;
        const long o1 = (long)l * FEAT * FEAT;
        const long o2 = (long)l * 3 * FEAT * FEAT;
        const long o3 = (long)l * FEAT * 2 * FEAT;

        // phi-MLP: s -> h (hi/lo), h -> phi (bf16 hi only, for gathers)
        gemm_ps_kernel<<<gN128, 256, 0, stream>>>(
            s_h, s_l, w1h + o1, w1l + o1, nullptr, nullptr, b1,
            nullptr, nullptr, h_h, h_l, N, FEAT, FEAT, 1);
        gemm_ps_kernel<<<gN384, 256, 0, stream>>>(
            h_h, h_l, w2h + o2, w2l + o2, nullptr, nullptr, b2,
            nullptr, nullptr, phi_b, nullptr, N, 3 * FEAT, FEAT, 0);

        // atomic-free message aggregation (phi bf16 gather, v fp32 gather)
        edge_aggr_kernel<<<N, 128, 0, stream>>>(
            off, csr_j, csr_env, csr_unit, csr_rbfe, phi_b, vold,
            dW, db, s, vnew, vnh, vnl, N, SP);

        // u_v and v_v in ONE dispatch: N=256, tile-y 0 = U rows, tile-y 1 = V
        gemm_ps_kernel<<<gUV, 256, 0, stream>>>(
            vnh, vnl, uh + o1, ul + o1, vh + o1, vl + o1, nullptr,
            u_v, v_v, nullptr, nullptr, 3 * N, 256, FEAT, 0);

        // gate MLP: cat -> h (hi/lo), h -> a (fp32)
        cat_norm_kernel<<<(SP + 255) / 256, 256, 0, stream>>>(
            s, v_v, cath, catl, SP);
        gemm_ps_kernel<<<gN128, 256, 0, stream>>>(
            cath, catl, sw1h + o3, sw1l + o3, nullptr, nullptr, sb1,
            nullptr, nullptr, h_h, h_l, N, FEAT, 2 * FEAT, 1);
        gemm_ps_kernel<<<gN384, 256, 0, stream>>>(
            h_h, h_l, sw2h + o2, sw2l + o2, nullptr, nullptr, sb2,
            a_buf, nullptr, nullptr, nullptr, N, 3 * FEAT, FEAT, 0);

        // final update ('a_buf' holds 'a'); refreshes s hi/lo for next layer
        update_sv_kernel<<<(SP + 255) / 256, 256, 0, stream>>>(
            s, s_h, s_l, vnew, u_v, v_v, a_buf, SP);

        float* tmp = vold; vold = vnew; vnew = tmp;
    }

    write_out_kernel<<<(SP + 255) / 256, 256, 0, stream>>>(vold, outv, SP);
}

// Round 9
// 983.218 us; speedup vs baseline: 1.1240x; 1.0603x over previous
//
#include <hip/hip_runtime.h>
#include <math.h>

#define FEAT 128
#define NRBF 20
#define NCONV 3
#define PI_F 3.14159265358979323846f

typedef __attribute__((ext_vector_type(8))) short short8;
typedef __attribute__((ext_vector_type(4))) float floatx4;
typedef unsigned short ushort_t;

__device__ inline float b2f(unsigned short u) {
    union { unsigned int i; float f; } c; c.i = ((unsigned int)u) << 16; return c.f;
}
__device__ inline unsigned short f2b(float x) {
    union { float f; unsigned int i; } c; c.f = x;
    unsigned int u = c.i;
    return (unsigned short)((u + 0x7fffu + ((u >> 16) & 1u)) >> 16);
}

// ---------------------------------------------------------------------------
// Fused 2-layer MLP: out[M,384] = silu(A1 @ W1^T + b1) @ W2^T + b2
// A1 = s[M,128] (phi mode) or [s | norm(vv)] [M,256] (gate mode, vv != null).
// Hidden h (128-wide = one K-tile) lives in LDS hi/lo; never touches HBM.
// Split-precision: acc += Ah*Wh + Ah*Wl + Al*Wh throughout.
// out: bf16-hi (out_b, phi mode) or fp32 (out_f, gate mode).
// 128-row m-tile, 256 thr = 4 waves, per-wave 64x64 via 4x4 16x16x32 MFMA.
// LDS: 4x10KB staging + 2x34.8KB h = 110 KB -> 1 block/CU.
// ---------------------------------------------------------------------------
__global__ __launch_bounds__(256) void mlp_fused_kernel(
    const float* __restrict__ s, const float* __restrict__ vv,
    const ushort_t* __restrict__ W1h, const ushort_t* __restrict__ W1l,
    const float* __restrict__ b1,
    const ushort_t* __restrict__ W2h, const ushort_t* __restrict__ W2l,
    const float* __restrict__ b2,
    ushort_t* __restrict__ out_b, float* __restrict__ out_f,
    int M, int K1, int SP)
{
    __shared__ __align__(16) ushort_t Ah[128 * 40];
    __shared__ __align__(16) ushort_t Al[128 * 40];
    __shared__ __align__(16) ushort_t Wh[128 * 40];
    __shared__ __align__(16) ushort_t Wl[128 * 40];
    __shared__ __align__(16) ushort_t Hh[128 * 136];
    __shared__ __align__(16) ushort_t Hl[128 * 136];

    const int t    = threadIdx.x;
    const int m0   = blockIdx.x * 128;
    const int wv   = t >> 6;
    const int lane = t & 63;
    const int wm   = (wv >> 1) * 64;
    const int wn   = (wv & 1) * 64;
    const int lr   = lane & 15;
    const int lk   = (lane >> 4) * 8;
    const int quad = lane >> 4;
    const int arow = t >> 3;          // 0..31, 4 passes of 32 rows
    const int acol = (t & 7) * 4;     // fp32 x4
    const int wrow = t >> 2;          // 0..63, 2 passes of 64 rows
    const int wcol = (t & 3) * 8;     // ushort x8

    floatx4 acc[4][4] = {};

    // ---- stage 1: h = silu(A1 @ W1^T + b1) ----
    for (int k0 = 0; k0 < K1; k0 += 32) {
        #pragma unroll
        for (int h = 0; h < 4; ++h) {
            int r = arow + h * 32;
            int m = m0 + r; if (m >= M) m = M - 1;   // clamp tail
            float xs[4];
            if (k0 < 128) {
                float4 av = *(const float4*)(s + (long)m * 128 + k0 + acol);
                xs[0] = av.x; xs[1] = av.y; xs[2] = av.z; xs[3] = av.w;
            } else {
                long base = (long)m * 128 + (k0 - 128 + acol);
                float4 a0 = *(const float4*)(vv + base);
                float4 a1 = *(const float4*)(vv + (long)SP + base);
                float4 a2 = *(const float4*)(vv + 2 * (long)SP + base);
                xs[0] = sqrtf(a0.x * a0.x + a1.x * a1.x + a2.x * a2.x);
                xs[1] = sqrtf(a0.y * a0.y + a1.y * a1.y + a2.y * a2.y);
                xs[2] = sqrtf(a0.z * a0.z + a1.z * a1.z + a2.z * a2.z);
                xs[3] = sqrtf(a0.w * a0.w + a1.w * a1.w + a2.w * a2.w);
            }
            unsigned short hh[4], ll[4];
            #pragma unroll
            for (int q = 0; q < 4; ++q) {
                hh[q] = f2b(xs[q]);
                ll[q] = f2b(xs[q] - b2f(hh[q]));
            }
            *(ushort4*)(&Ah[r * 40 + acol]) = make_ushort4(hh[0], hh[1], hh[2], hh[3]);
            *(ushort4*)(&Al[r * 40 + acol]) = make_ushort4(ll[0], ll[1], ll[2], ll[3]);
        }
        #pragma unroll
        for (int h = 0; h < 2; ++h) {
            int r = wrow + h * 64;
            *(uint4*)(&Wh[r * 40 + wcol]) =
                *(const uint4*)(W1h + (long)r * K1 + k0 + wcol);
            *(uint4*)(&Wl[r * 40 + wcol]) =
                *(const uint4*)(W1l + (long)r * K1 + k0 + wcol);
        }
        __syncthreads();
        short8 af[4], alf[4], wf[4], wlf[4];
        #pragma unroll
        for (int i = 0; i < 4; ++i) {
            af[i]  = *(const short8*)(&Ah[(wm + i * 16 + lr) * 40 + lk]);
            alf[i] = *(const short8*)(&Al[(wm + i * 16 + lr) * 40 + lk]);
            wf[i]  = *(const short8*)(&Wh[(wn + i * 16 + lr) * 40 + lk]);
            wlf[i] = *(const short8*)(&Wl[(wn + i * 16 + lr) * 40 + lk]);
        }
        #pragma unroll
        for (int i = 0; i < 4; ++i)
            #pragma unroll
            for (int j = 0; j < 4; ++j) {
                acc[i][j] = __builtin_amdgcn_mfma_f32_16x16x32_bf16(
                    af[i], wf[j], acc[i][j], 0, 0, 0);
                acc[i][j] = __builtin_amdgcn_mfma_f32_16x16x32_bf16(
                    af[i], wlf[j], acc[i][j], 0, 0, 0);
                acc[i][j] = __builtin_amdgcn_mfma_f32_16x16x32_bf16(
                    alf[i], wf[j], acc[i][j], 0, 0, 0);
            }
        __syncthreads();
    }

    // stage-1 epilogue -> h in LDS (hi/lo), C/D layout col=lane&15, row=quad*4+r
    #pragma unroll
    for (int i = 0; i < 4; ++i)
        #pragma unroll
        for (int r = 0; r < 4; ++r) {
            int mrow = wm + i * 16 + quad * 4 + r;
            #pragma unroll
            for (int j = 0; j < 4; ++j) {
                int kcol = wn + j * 16 + lr;
                float x = acc[i][j][r] + b1[kcol];
                x *= 1.f / (1.f + __expf(-x));
                unsigned short hh = f2b(x);
                Hh[mrow * 136 + kcol] = hh;
                Hl[mrow * 136 + kcol] = f2b(x - b2f(hh));
            }
        }

    // ---- stage 2: out = h @ W2^T + b2, 3 n-tiles of 128 ----
    for (int nt = 0; nt < 3; ++nt) {
        #pragma unroll
        for (int i = 0; i < 4; ++i)
            #pragma unroll
            for (int j = 0; j < 4; ++j)
                #pragma unroll
                for (int q = 0; q < 4; ++q) acc[i][j][q] = 0.f;
        for (int k0 = 0; k0 < 128; k0 += 32) {
            __syncthreads();   // guard Wh/Wl overwrite (and H writes on 1st pass)
            #pragma unroll
            for (int h = 0; h < 2; ++h) {
                int r = wrow + h * 64;
                long wo = (long)(nt * 128 + r) * 128;
                *(uint4*)(&Wh[r * 40 + wcol]) = *(const uint4*)(W2h + wo + k0 + wcol);
                *(uint4*)(&Wl[r * 40 + wcol]) = *(const uint4*)(W2l + wo + k0 + wcol);
            }
            __syncthreads();
            short8 af[4], alf[4], wf[4], wlf[4];
            #pragma unroll
            for (int i = 0; i < 4; ++i) {
                af[i]  = *(const short8*)(&Hh[(wm + i * 16 + lr) * 136 + k0 + lk]);
                alf[i] = *(const short8*)(&Hl[(wm + i * 16 + lr) * 136 + k0 + lk]);
                wf[i]  = *(const short8*)(&Wh[(wn + i * 16 + lr) * 40 + lk]);
                wlf[i] = *(const short8*)(&Wl[(wn + i * 16 + lr) * 40 + lk]);
            }
            #pragma unroll
            for (int i = 0; i < 4; ++i)
                #pragma unroll
                for (int j = 0; j < 4; ++j) {
                    acc[i][j] = __builtin_amdgcn_mfma_f32_16x16x32_bf16(
                        af[i], wf[j], acc[i][j], 0, 0, 0);
                    acc[i][j] = __builtin_amdgcn_mfma_f32_16x16x32_bf16(
                        af[i], wlf[j], acc[i][j], 0, 0, 0);
                    acc[i][j] = __builtin_amdgcn_mfma_f32_16x16x32_bf16(
                        alf[i], wf[j], acc[i][j], 0, 0, 0);
                }
        }
        #pragma unroll
        for (int i = 0; i < 4; ++i)
            #pragma unroll
            for (int r = 0; r < 4; ++r) {
                int m = m0 + wm + i * 16 + quad * 4 + r;
                if (m >= M) continue;
                #pragma unroll
                for (int j = 0; j < 4; ++j) {
                    int n = nt * 128 + wn + j * 16 + lr;
                    float x = acc[i][j][r] + b2[n];
                    if (out_b) out_b[(long)m * 384 + n] = f2b(x);
                    else       out_f[(long)m * 384 + n] = x;
                }
            }
    }
}

// ---------------------------------------------------------------------------
// Pre-split MFMA GEMM (UV only): dual weights, fp32 C0/C1 routing by n-tile.
// ---------------------------------------------------------------------------
__global__ __launch_bounds__(256) void gemm_ps_kernel(
    const ushort_t* __restrict__ Ahg, const ushort_t* __restrict__ Alg,
    const ushort_t* __restrict__ Whi, const ushort_t* __restrict__ Wlo,
    const ushort_t* __restrict__ W2h, const ushort_t* __restrict__ W2l,
    float* __restrict__ C0, float* __restrict__ C1,
    int M, int K)
{
    __shared__ __align__(16) ushort_t Ah[128 * 40];
    __shared__ __align__(16) ushort_t Al[128 * 40];
    __shared__ __align__(16) ushort_t Wh[128 * 40];
    __shared__ __align__(16) ushort_t Wl[128 * 40];
    const int t    = threadIdx.x;
    const int m0   = blockIdx.x * 128;
    const int nt   = blockIdx.y;          // 0 -> U/C0, 1 -> V/C1
    const int wv   = t >> 6;
    const int lane = t & 63;
    const int wm   = (wv >> 1) * 64;
    const int wn   = (wv & 1) * 64;
    const int lr   = lane & 15;
    const int lk   = (lane >> 4) * 8;
    const int srow = t >> 2;
    const int scol = (t & 3) * 8;
    const ushort_t* Wsh = nt ? W2h : Whi;
    const ushort_t* Wsl = nt ? W2l : Wlo;

    floatx4 acc[4][4] = {};

    for (int k0 = 0; k0 < K; k0 += 32) {
        #pragma unroll
        for (int h = 0; h < 2; ++h) {
            int r = srow + h * 64;
            int m = m0 + r; if (m >= M) m = M - 1;
            *(uint4*)(&Ah[r * 40 + scol]) =
                *(const uint4*)(Ahg + (long)m * K + k0 + scol);
            *(uint4*)(&Al[r * 40 + scol]) =
                *(const uint4*)(Alg + (long)m * K + k0 + scol);
            *(uint4*)(&Wh[r * 40 + scol]) =
                *(const uint4*)(Wsh + (long)r * K + k0 + scol);
            *(uint4*)(&Wl[r * 40 + scol]) =
                *(const uint4*)(Wsl + (long)r * K + k0 + scol);
        }
        __syncthreads();
        short8 ah[4], al[4], wh[4], wl[4];
        #pragma unroll
        for (int i = 0; i < 4; ++i) {
            ah[i] = *(const short8*)(&Ah[(wm + i * 16 + lr) * 40 + lk]);
            al[i] = *(const short8*)(&Al[(wm + i * 16 + lr) * 40 + lk]);
            wh[i] = *(const short8*)(&Wh[(wn + i * 16 + lr) * 40 + lk]);
            wl[i] = *(const short8*)(&Wl[(wn + i * 16 + lr) * 40 + lk]);
        }
        #pragma unroll
        for (int i = 0; i < 4; ++i)
            #pragma unroll
            for (int j = 0; j < 4; ++j) {
                acc[i][j] = __builtin_amdgcn_mfma_f32_16x16x32_bf16(
                    ah[i], wh[j], acc[i][j], 0, 0, 0);
                acc[i][j] = __builtin_amdgcn_mfma_f32_16x16x32_bf16(
                    ah[i], wl[j], acc[i][j], 0, 0, 0);
                acc[i][j] = __builtin_amdgcn_mfma_f32_16x16x32_bf16(
                    al[i], wh[j], acc[i][j], 0, 0, 0);
            }
        __syncthreads();
    }

    float* C = nt ? C1 : C0;
    #pragma unroll
    for (int i = 0; i < 4; ++i)
        #pragma unroll
        for (int r = 0; r < 4; ++r) {
            int m = m0 + wm + i * 16 + (lane >> 4) * 4 + r;
            if (m >= M) continue;
            #pragma unroll
            for (int j = 0; j < 4; ++j) {
                int n = wn + j * 16 + lr;
                C[(long)m * 128 + n] = acc[i][j][r];
            }
        }
}

// ---------------------------------------------------------------------------
__global__ __launch_bounds__(256) void split_kernel(
    const float* __restrict__ src, ushort_t* __restrict__ hi,
    ushort_t* __restrict__ lo, int n)
{
    int i = blockIdx.x * blockDim.x + threadIdx.x;
    if (i >= n) return;
    float x = src[i];
    unsigned short h = f2b(x);
    hi[i] = h;
    lo[i] = f2b(x - b2f(h));
}

// ---------------------------------------------------------------------------
// CSR build
// ---------------------------------------------------------------------------
__global__ __launch_bounds__(256) void hist_kernel(
    const int* __restrict__ nbr, int* __restrict__ deg, int Ed)
{
    int e = blockIdx.x * blockDim.x + threadIdx.x;
    if (e >= Ed) return;
    int E = Ed >> 1;
    int i = (e < E) ? nbr[2 * e] : nbr[2 * (e - E) + 1];
    atomicAdd(&deg[i], 1);
}

__device__ inline int wave_incl_scan(int x, int lane)
{
    #pragma unroll
    for (int s = 1; s < 64; s <<= 1) {
        int y = __shfl_up(x, s, 64);
        if (lane >= s) x += y;
    }
    return x;
}

__global__ __launch_bounds__(1024) void scan_kernel(
    const int* __restrict__ deg, int* __restrict__ off,
    int* __restrict__ cursor, int N)
{
    __shared__ int wsum[16];
    __shared__ int carry_s;
    const int t = threadIdx.x;
    const int lane = t & 63;
    const int w = t >> 6;
    if (t == 0) { carry_s = 0; off[0] = 0; }
    __syncthreads();
    for (int base = 0; base < N; base += 1024) {
        int i = base + t;
        int x = (i < N) ? deg[i] : 0;
        int sc = wave_incl_scan(x, lane);
        if (lane == 63) wsum[w] = sc;
        __syncthreads();
        if (w == 0) {
            int v = (lane < 16) ? wsum[lane] : 0;
            int vs = wave_incl_scan(v, lane);
            if (lane < 16) wsum[lane] = vs;
        }
        __syncthreads();
        int waveoff = (w > 0) ? wsum[w - 1] : 0;
        int inc = sc + waveoff + carry_s;
        if (i < N) { off[i + 1] = inc; cursor[i] = inc - x; }
        __syncthreads();
        if (t == 1023) carry_s = inc;
        __syncthreads();
    }
}

__global__ __launch_bounds__(256) void scatter_geom_kernel(
    const int* __restrict__ nbr, const float* __restrict__ xyz,
    int* __restrict__ cursor, int* __restrict__ csr_j,
    float* __restrict__ csr_env, float* __restrict__ csr_unit,
    float* __restrict__ csr_rbfe, int Ed)
{
    int e = blockIdx.x * blockDim.x + threadIdx.x;
    if (e >= Ed) return;
    int E = Ed >> 1;
    int i, j;
    if (e < E) { i = nbr[2 * e];         j = nbr[2 * e + 1]; }
    else       { int u = e - E; i = nbr[2 * u + 1]; j = nbr[2 * u]; }

    int p = atomicAdd(&cursor[i], 1);
    csr_j[p] = j;

    float rx = xyz[3 * j + 0] - xyz[3 * i + 0];
    float ry = xyz[3 * j + 1] - xyz[3 * i + 1];
    float rz = xyz[3 * j + 2] - xyz[3 * i + 2];
    float d   = sqrtf(rx * rx + ry * ry + rz * rz);
    float inv = 1.f / d;
    csr_unit[3 * p + 0] = rx * inv;
    csr_unit[3 * p + 1] = ry * inv;
    csr_unit[3 * p + 2] = rz * inv;
    float ev = (d < 20.f) ? 0.5f * (__cosf(PI_F * d / 20.f) + 1.f) : 0.f;
    csr_env[p] = ev;
    float base = PI_F * d / 20.f;
    #pragma unroll
    for (int k = 0; k < NRBF; ++k)
        csr_rbfe[(long)p * NRBF + k] = ev * __sinf((float)(k + 1) * base) * inv;
}

// ---------------------------------------------------------------------------
// Edge aggregation (unchanged from R8): phi bf16 gather, v fp32 gather,
// emits vnh/vnl for the UV GEMM.
// ---------------------------------------------------------------------------
__global__ __launch_bounds__(128) void edge_aggr_kernel(
    const int* __restrict__ off, const int* __restrict__ csr_j,
    const float* __restrict__ csr_env, const float* __restrict__ csr_unit,
    const float* __restrict__ csr_rbfe,
    const ushort_t* __restrict__ phib, const float* __restrict__ vold,
    const float* __restrict__ distW, const float* __restrict__ distb,
    float* __restrict__ s, float* __restrict__ vnew,
    ushort_t* __restrict__ vnh, ushort_t* __restrict__ vnl, int N, int SP)
{
    const int f = threadIdx.x;
    float w0c[NRBF], w1c[NRBF], w2c[NRBF];
    const float b0 = distb[f];
    const float b1 = distb[128 + f];
    const float b2 = distb[256 + f];
    #pragma unroll
    for (int k = 0; k < NRBF; ++k) {
        w0c[k] = distW[(long)f * NRBF + k];
        w1c[k] = distW[(long)(128 + f) * NRBF + k];
        w2c[k] = distW[(long)(256 + f) * NRBF + k];
    }

    for (int node = blockIdx.x; node < N; node += gridDim.x) {
        const int p0 = off[node], p1 = off[node + 1];
        float ssum = 0.f, v0 = 0.f, v1 = 0.f, v2 = 0.f;
        for (int p = p0; p < p1; ++p) {
            int j = csr_j[p];
            float ev = csr_env[p];
            float ux = csr_unit[3 * p + 0];
            float uy = csr_unit[3 * p + 1];
            float uz = csr_unit[3 * p + 2];
            const float* rb = csr_rbfe + (long)p * NRBF;
            float w0 = ev * b0, w1 = ev * b1, w2 = ev * b2;
            #pragma unroll
            for (int k = 0; k < NRBF; ++k) {
                float r = rb[k];
                w0 += r * w0c[k];
                w1 += r * w1c[k];
                w2 += r * w2c[k];
            }
            long jb = (long)j * 384;
            float i0 = b2f(phib[jb + f])       * w0;
            float i1 = b2f(phib[jb + 128 + f]) * w1;
            float i2 = b2f(phib[jb + 256 + f]) * w2;
            long jv = (long)j * FEAT + f;
            ssum += i1;
            v0 += i2 * ux + i0 * vold[jv];
            v1 += i2 * uy + i0 * vold[SP + jv];
            v2 += i2 * uz + i0 * vold[2 * SP + jv];
        }
        long iv = (long)node * FEAT + f;
        s[iv] += ssum;
        float n0 = vold[iv]          + v0;
        float n1 = vold[SP + iv]     + v1;
        float n2 = vold[2 * SP + iv] + v2;
        vnew[iv]          = n0;
        vnew[SP + iv]     = n1;
        vnew[2 * SP + iv] = n2;
        unsigned short h0 = f2b(n0), h1 = f2b(n1), h2 = f2b(n2);
        vnh[iv]          = h0;  vnl[iv]          = f2b(n0 - b2f(h0));
        vnh[SP + iv]     = h1;  vnl[SP + iv]     = f2b(n1 - b2f(h1));
        vnh[2 * SP + iv] = h2;  vnl[2 * SP + iv] = f2b(n2 - b2f(h2));
    }
}

// ---------------------------------------------------------------------------
// Elementwise kernels
// ---------------------------------------------------------------------------
__global__ __launch_bounds__(256) void init_s_kernel(
    const float* __restrict__ cg_s, float* __restrict__ s,
    float* __restrict__ vA, int nS, int nV)
{
    int idx = blockIdx.x * blockDim.x + threadIdx.x;
    if (idx < nS) s[idx] = cg_s[idx];
    if (idx < nV) vA[idx] = 0.f;
}

// final: if outv != null, v result goes interleaved to outv (and v not written)
__global__ __launch_bounds__(256) void update_sv_kernel(
    float* __restrict__ s, float* __restrict__ v,
    const float* __restrict__ uv, const float* __restrict__ vv,
    const float* __restrict__ a, float* __restrict__ outv, int SP)
{
    int idx = blockIdx.x * blockDim.x + threadIdx.x;
    if (idx >= SP) return;
    int n = idx >> 7, g = idx & 127;
    float u0 = uv[idx], u1 = uv[SP + idx], u2 = uv[2 * SP + idx];
    float w0 = vv[idx], w1 = vv[SP + idx], w2 = vv[2 * SP + idx];
    long ab = (long)n * 384;
    float dot = u0 * w0 + u1 * w1 + u2 * w2;
    s[idx] += dot * a[ab + 128 + g] + a[ab + 256 + g];
    float g0 = a[ab + g];
    float x0 = v[idx] + u0 * g0;
    float x1 = v[SP + idx] + u1 * g0;
    float x2 = v[2 * SP + idx] + u2 * g0;
    if (outv) {
        outv[(long)idx * 3 + 0] = x0;
        outv[(long)idx * 3 + 1] = x1;
        outv[(long)idx * 3 + 2] = x2;
    } else {
        v[idx]          = x0;
        v[SP + idx]     = x1;
        v[2 * SP + idx] = x2;
    }
}

// ---------------------------------------------------------------------------
extern "C" void kernel_launch(void* const* d_in, const int* in_sizes, int n_in,
                              void* d_out, int out_size, void* d_ws, size_t ws_size,
                              hipStream_t stream)
{
    const float* xyz     = (const float*)d_in[0];
    const int*   nbr     = (const int*)  d_in[1];
    const float* cg_s    = (const float*)d_in[2];
    const float* msg_W1  = (const float*)d_in[3];
    const float* msg_b1  = (const float*)d_in[4];
    const float* msg_W2  = (const float*)d_in[5];
    const float* msg_b2  = (const float*)d_in[6];
    const float* dist_W  = (const float*)d_in[7];
    const float* dist_b  = (const float*)d_in[8];
    const float* upd_U   = (const float*)d_in[9];
    const float* upd_V   = (const float*)d_in[10];
    const float* upd_sW1 = (const float*)d_in[11];
    const float* upd_sb1 = (const float*)d_in[12];
    const float* upd_sW2 = (const float*)d_in[13];
    const float* upd_sb2 = (const float*)d_in[14];

    const int E  = in_sizes[1] / 2;
    const int Ed = 2 * E;
    const int N  = in_sizes[2] / FEAT;
    const int SP = N * FEAT;

    float* s    = (float*)d_out;
    float* outv = (float*)d_out + (long)SP;

    // workspace carve-up
    float* w = (float*)d_ws;
    size_t off_ = 0;
    auto alloc = [&](size_t nelem) {
        float* p = w + off_;
        off_ += (nelem + 255) & ~(size_t)255;
        return p;
    };
    auto allocb = [&](size_t nelem) {
        return (ushort_t*)alloc((nelem + 1) / 2);
    };
    int*   deg      = (int*)alloc((size_t)N);
    int*   off      = (int*)alloc((size_t)N + 1);
    int*   cursor   = (int*)alloc((size_t)N);
    int*   csr_j    = (int*)alloc((size_t)Ed);
    float* csr_env  = alloc((size_t)Ed);
    float* csr_unit = alloc((size_t)Ed * 3);
    float* csr_rbfe = alloc((size_t)Ed * NRBF);
    float* a_buf    = alloc((size_t)N * 384);
    float* u_v      = alloc((size_t)3 * SP);
    float* v_v      = alloc((size_t)3 * SP);
    float* vA       = alloc((size_t)3 * SP);
    float* vB       = alloc((size_t)3 * SP);
    ushort_t* phi_b = allocb((size_t)N * 384);
    ushort_t* vnh   = allocb((size_t)3 * SP);
    ushort_t* vnl   = allocb((size_t)3 * SP);
    const int n1 = NCONV * FEAT * FEAT;
    const int n2 = NCONV * 3 * FEAT * FEAT;
    const int n3 = NCONV * FEAT * 2 * FEAT;
    ushort_t* w1h  = allocb((size_t)n1);
    ushort_t* w1l  = allocb((size_t)n1);
    ushort_t* w2h  = allocb((size_t)n2);
    ushort_t* w2l  = allocb((size_t)n2);
    ushort_t* uh   = allocb((size_t)n1);
    ushort_t* ul   = allocb((size_t)n1);
    ushort_t* vh   = allocb((size_t)n1);
    ushort_t* vl   = allocb((size_t)n1);
    ushort_t* sw1h = allocb((size_t)n3);
    ushort_t* sw1l = allocb((size_t)n3);
    ushort_t* sw2h = allocb((size_t)n2);
    ushort_t* sw2l = allocb((size_t)n2);
    (void)ws_size; (void)n_in; (void)out_size;

    // weight split (once per launch)
    split_kernel<<<(n1 + 255) / 256, 256, 0, stream>>>(msg_W1, w1h, w1l, n1);
    split_kernel<<<(n2 + 255) / 256, 256, 0, stream>>>(msg_W2, w2h, w2l, n2);
    split_kernel<<<(n1 + 255) / 256, 256, 0, stream>>>(upd_U, uh, ul, n1);
    split_kernel<<<(n1 + 255) / 256, 256, 0, stream>>>(upd_V, vh, vl, n1);
    split_kernel<<<(n3 + 255) / 256, 256, 0, stream>>>(upd_sW1, sw1h, sw1l, n3);
    split_kernel<<<(n2 + 255) / 256, 256, 0, stream>>>(upd_sW2, sw2h, sw2l, n2);

    // init s <- cg_s, vA <- 0
    {
        int n = 3 * SP;
        init_s_kernel<<<(n + 255) / 256, 256, 0, stream>>>(cg_s, s, vA, SP, n);
    }

    // CSR build (once per launch)
    hipMemsetAsync(deg, 0, (size_t)N * sizeof(int), stream);
    hist_kernel<<<(Ed + 255) / 256, 256, 0, stream>>>(nbr, deg, Ed);
    scan_kernel<<<1, 1024, 0, stream>>>(deg, off, cursor, N);
    scatter_geom_kernel<<<(Ed + 255) / 256, 256, 0, stream>>>(
        nbr, xyz, cursor, csr_j, csr_env, csr_unit, csr_rbfe, Ed);

    float* vold = vA;
    float* vnew = vB;
    dim3 gM((N + 127) / 128, 1);
    dim3 gUV((3 * N + 127) / 128, 2);

    for (int l = 0; l < NCONV; ++l) {
        const float* b1  = msg_b1  + (long)l * FEAT;
        const float* b2  = msg_b2  + (long)l * 3 * FEAT;
        const float* dW  = dist_W  + (long)l * 3 * FEAT * NRBF;
        const float* db  = dist_b  + (long)l * 3 * FEAT;
        const float* sb1 = upd_sb1 + (long)l * FEAT;
        const float* sb2 = upd_sb2 + (long)l * 3 * FEAT;
        const long o1 = (long)l * FEAT * FEAT;
        const long o2 = (long)l * 3 * FEAT * FEAT;
        const long o3 = (long)l * FEAT * 2 * FEAT;

        // fused phi-MLP: s -> (h in LDS) -> phi_b (bf16 hi)
        mlp_fused_kernel<<<gM, 256, 0, stream>>>(
            s, nullptr, w1h + o1, w1l + o1, b1, w2h + o2, w2l + o2, b2,
            phi_b, nullptr, N, FEAT, SP);

        // atomic-free message aggregation
        edge_aggr_kernel<<<N, 128, 0, stream>>>(
            off, csr_j, csr_env, csr_unit, csr_rbfe, phi_b, vold,
            dW, db, s, vnew, vnh, vnl, N, SP);

        // u_v / v_v in one dispatch (y=0 -> U, y=1 -> V)
        gemm_ps_kernel<<<gUV, 256, 0, stream>>>(
            vnh, vnl, uh + o1, ul + o1, vh + o1, vl + o1,
            u_v, v_v, 3 * N, FEAT);

        // fused gate-MLP: [s | norm(v_v)] -> (h in LDS) -> a_buf (fp32)
        mlp_fused_kernel<<<gM, 256, 0, stream>>>(
            s, v_v, sw1h + o3, sw1l + o3, sb1, sw2h + o2, sw2l + o2, sb2,
            nullptr, a_buf, N, 2 * FEAT, SP);

        // final update; last layer writes v interleaved straight to output
        float* ov = (l == NCONV - 1) ? outv : nullptr;
        update_sv_kernel<<<(SP + 255) / 256, 256, 0, stream>>>(
            s, vnew, u_v, v_v, a_buf, ov, SP);

        float* tmp = vold; vold = vnew; vnew = tmp;
    }
}